// Round 1
// baseline (131.695 us; speedup 1.0000x reference)
//
#include <hip/hip_runtime.h>

// SpectralConv2d via pruned partial DFTs.
// x: [16,32,256,256] f32 ; w1,w2: [32,32,12,12,2] f32 ; out: [16,32,256,256] f32
// Pipeline:
//  K1: X1[bi][c][h]     = partial W-DFT of x          (c = 2*kx + {re,im}, kx 0..11)
//  K2: X[ky][kx][bi]    = partial H-DFT (ky slots: 0..11 low, 12..23 = rows 244..255)
//  K3: F[ky][kx][bo]    = channel mix (complex), scale (kx==0?1:2)/65536 folded in
//  K4: G[bo][h][c]      = inverse ky-DFT (exact complex ifft over the 24 modes)
//  K5: out[bo][h][w]    = inverse W-DFT (real output, Hermitian doubling prefolded)

#define TPI 6.28318530717958647692f

__global__ __launch_bounds__(256) void k1_wdft(const float* __restrict__ x,
                                               float* __restrict__ X1) {
  __shared__ float tile[256 * 33];   // [row][w-panel 32], pad 33 (bank-spread)
  __shared__ float twred[6400];      // union: tw[256][24] (6144) / red[4][64][25] (6400)
  const int bi = blockIdx.x;         // 0..511  (b*32 + i)
  const int t = threadIdx.x;
  const int l = t & 63, wq = t >> 6;

  // build twiddle table: tw[w][2*kx] = cos(2pi kx w/256), tw[w][2*kx+1] = -sin(...)
  for (int e = t; e < 256 * 12; e += 256) {
    int w = e & 255, kx = e >> 8;
    float sv, cv;
    sincosf(TPI * (float)((w * kx) & 255) * (1.0f / 256.0f), &sv, &cv);
    twred[w * 24 + 2 * kx] = cv;
    twred[w * 24 + 2 * kx + 1] = -sv;
  }

  float acc[4][24];
#pragma unroll
  for (int g = 0; g < 4; g++)
#pragma unroll
    for (int c = 0; c < 24; c++) acc[g][c] = 0.0f;

  const float4* xg4 = reinterpret_cast<const float4*>(x + (size_t)bi * 65536);

  for (int p = 0; p < 8; p++) {      // 8 panels of 32 w
    __syncthreads();                 // protect tile from previous panel readers (and order tw build)
    for (int k = 0; k < 8; k++) {
      int flat = k * 256 + t;        // 0..2047
      int row = flat >> 3, wq4 = flat & 7;
      float4 v = xg4[row * 64 + p * 8 + wq4];
      int base = row * 33 + wq4 * 4;
      tile[base + 0] = v.x; tile[base + 1] = v.y;
      tile[base + 2] = v.z; tile[base + 3] = v.w;
    }
    __syncthreads();
    for (int wsi = 0; wsi < 8; wsi++) {
      int wloc = wq * 8 + wsi;
      int wglob = p * 32 + wloc;
      float twr[24];
      const float4* twrow = reinterpret_cast<const float4*>(&twred[wglob * 24]);
#pragma unroll
      for (int q = 0; q < 6; q++) {
        float4 v = twrow[q];
        twr[4 * q] = v.x; twr[4 * q + 1] = v.y; twr[4 * q + 2] = v.z; twr[4 * q + 3] = v.w;
      }
#pragma unroll
      for (int g = 0; g < 4; g++) {
        float xv = tile[(l + 64 * g) * 33 + wloc];
#pragma unroll
        for (int c = 0; c < 24; c++) acc[g][c] = fmaf(xv, twr[c], acc[g][c]);
      }
    }
  }

  // cross-wave reduce (4 w-subrange partials per row) and write X1
  for (int g = 0; g < 4; g++) {
    __syncthreads();
#pragma unroll
    for (int c = 0; c < 24; c++) twred[(wq * 64 + l) * 25 + c] = acc[g][c];
    __syncthreads();
    for (int f = t; f < 1536; f += 256) {
      int c = f >> 6, lw = f & 63;
      float s = twred[lw * 25 + c] + twred[(64 + lw) * 25 + c] +
                twred[(128 + lw) * 25 + c] + twred[(192 + lw) * 25 + c];
      X1[((size_t)bi * 24 + c) * 256 + g * 64 + lw] = s;
    }
  }
}

__global__ __launch_bounds__(256) void k2_hdft(const float* __restrict__ X1,
                                               float* __restrict__ Xf) {
  int gid = blockIdx.x * 256 + threadIdx.x;  // exactly 79872 threads
  int bi = gid / 156, rem = gid % 156;       // 156 = 13 |ky| * 12 kx
  int j = rem / 12, kx = rem % 12;           // j = |ky| in 0..12
  const float* rr = X1 + ((size_t)bi * 24 + 2 * kx) * 256;
  const float* ri = rr + 256;
  float cs, ss;
  {
    float s, c;
    sincosf(TPI * (float)j * (1.0f / 256.0f), &s, &c);
    cs = c; ss = -s;                          // step phasor e^{-i j theta}
  }
  float pr = 1.0f, pi = 0.0f;                 // p = e^{-i j theta h}
  float a1 = 0, a2 = 0, a3 = 0, a4 = 0;
  for (int h = 0; h < 256; h += 4) {
    float4 xr4 = *reinterpret_cast<const float4*>(rr + h);
    float4 xi4 = *reinterpret_cast<const float4*>(ri + h);
#pragma unroll
    for (int u = 0; u < 4; u++) {
      float xr = (&xr4.x)[u], xi = (&xi4.x)[u];
      a1 = fmaf(xr, pr, a1);   // sum xr*cos
      a2 = fmaf(xi, pr, a2);   // sum xi*cos
      a3 = fmaf(xr, pi, a3);   // -sum xr*sin
      a4 = fmaf(xi, pi, a4);   // -sum xi*sin
      float npr = pr * cs - pi * ss;
      float npi = pr * ss + pi * cs;
      pr = npr; pi = npi;
    }
  }
  // X[j]     (low,  e^{-i j th h}):  re = a1 - a4, im = a2 + a3
  // X[256-j] (high, e^{+i j th h}):  re = a1 + a4, im = a2 - a3  -> slot 24-j
  float2* Xo = reinterpret_cast<float2*>(Xf);
  size_t base = (size_t)kx * 512 + bi;
  if (j <= 11) Xo[(size_t)j * 12 * 512 + base] = make_float2(a1 - a4, a2 + a3);
  if (j >= 1)  Xo[(size_t)(24 - j) * 12 * 512 + base] = make_float2(a1 + a4, a2 - a3);
}

__global__ __launch_bounds__(256) void k3_mix(const float* __restrict__ Xf,
                                              const float* __restrict__ w1,
                                              const float* __restrict__ w2,
                                              float* __restrict__ Ff) {
  __shared__ float Xs[1024];  // [b][i][2]
  __shared__ float Ws[2048];  // [i][o][2]
  int m = blockIdx.x;         // ky*12 + kx, 288 blocks
  int ky = m / 12, kx = m % 12;
  int t = threadIdx.x;
  const float* Xsl = Xf + (size_t)m * 1024;
  for (int e = t; e < 1024; e += 256) Xs[e] = Xsl[e];
  const float* Wp = (ky < 12) ? w1 : w2;
  int myr = (ky < 12) ? ky : ky - 12;
  int woff = myr * 24 + kx * 2;
  for (int e = t; e < 1024; e += 256) {  // e = i*32 + o
    float2 wv = *reinterpret_cast<const float2*>(Wp + (size_t)e * 288 + woff);
    Ws[e * 2] = wv.x; Ws[e * 2 + 1] = wv.y;
  }
  __syncthreads();
  int o = t & 31, bh = t >> 5;  // bh 0..7 ; handles b = bh and bh+8
  float ar = 0, ai = 0, br = 0, bi_ = 0;
#pragma unroll
  for (int i = 0; i < 32; i++) {
    float wr = Ws[i * 64 + o * 2], wi = Ws[i * 64 + o * 2 + 1];
    float x1r = Xs[bh * 64 + i * 2], x1i = Xs[bh * 64 + i * 2 + 1];
    float x2r = Xs[(bh + 8) * 64 + i * 2], x2i = Xs[(bh + 8) * 64 + i * 2 + 1];
    ar = fmaf(x1r, wr, ar); ar = fmaf(-x1i, wi, ar);
    ai = fmaf(x1r, wi, ai); ai = fmaf(x1i, wr, ai);
    br = fmaf(x2r, wr, br); br = fmaf(-x2i, wi, br);
    bi_ = fmaf(x2r, wi, bi_); bi_ = fmaf(x2i, wr, bi_);
  }
  float scale = (kx == 0 ? 1.0f : 2.0f) * (1.0f / 65536.0f);
  float2* Fo = reinterpret_cast<float2*>(Ff) + (size_t)m * 512;
  Fo[(size_t)bh * 32 + o] = make_float2(ar * scale, ai * scale);
  Fo[(size_t)(bh + 8) * 32 + o] = make_float2(br * scale, bi_ * scale);
}

__global__ __launch_bounds__(192) void k4_ihdft(const float* __restrict__ Ff,
                                                float* __restrict__ G) {
  __shared__ float tw[16 * 13 * 2];  // [hh][j][{cos,sin}]
  int bg = blockIdx.x >> 3, hg = blockIdx.x & 7;  // 32 bo-groups x 8 h-groups
  int t = threadIdx.x;                            // 0..191
  for (int e = t; e < 16 * 13; e += 192) {
    int hh = e / 13, j = e % 13;
    float s, c;
    sincosf(TPI * (float)(((hg * 16 + hh) * j) & 255) * (1.0f / 256.0f), &s, &c);
    tw[e * 2] = c; tw[e * 2 + 1] = s;
  }
  int kx = t % 12, bl = t / 12;
  int bo = bg * 16 + bl;
  // P = F_low + F_high ; Q = i(F_low - F_high)
  float Pr[13], Pi[13], Qr[13], Qi[13];
  const float2* F2 = reinterpret_cast<const float2*>(Ff);
#pragma unroll
  for (int j = 0; j < 13; j++) {
    float lr = 0, li = 0, hr = 0, hi = 0;
    if (j < 12) { float2 v = F2[((size_t)j * 12 + kx) * 512 + bo]; lr = v.x; li = v.y; }
    if (j > 0)  { float2 v = F2[((size_t)(24 - j) * 12 + kx) * 512 + bo]; hr = v.x; hi = v.y; }
    Pr[j] = lr + hr; Pi[j] = li + hi;
    Qr[j] = hi - li; Qi[j] = lr - hr;
  }
  __syncthreads();
  float2* Go = reinterpret_cast<float2*>(G);
  for (int hh = 0; hh < 16; hh++) {
    int h = hg * 16 + hh;
    float Er = 0, Ei = 0, Or = 0, Oi = 0;  // even-j / odd-j partial sums
#pragma unroll
    for (int j = 0; j < 13; j++) {
      float c = tw[(hh * 13 + j) * 2], s = tw[(hh * 13 + j) * 2 + 1];
      if (j & 1) {
        Or = fmaf(Pr[j], c, Or); Or = fmaf(Qr[j], s, Or);
        Oi = fmaf(Pi[j], c, Oi); Oi = fmaf(Qi[j], s, Oi);
      } else {
        Er = fmaf(Pr[j], c, Er); Er = fmaf(Qr[j], s, Er);
        Ei = fmaf(Pi[j], c, Ei); Ei = fmaf(Qi[j], s, Ei);
      }
    }
    // G[h] = E + O ; G[h+128] = E - O   (e^{+-i j pi} = (-1)^j)
    size_t r0 = ((size_t)bo * 256 + h) * 12 + kx;
    size_t r1 = ((size_t)bo * 256 + h + 128) * 12 + kx;
    Go[r0] = make_float2(Er + Or, Ei + Oi);
    Go[r1] = make_float2(Er - Or, Ei - Oi);
  }
}

__global__ __launch_bounds__(256) void k5_iwdft(const float* __restrict__ G,
                                                float* __restrict__ out) {
  __shared__ float Gs[64 * 24];
  int blk = blockIdx.x;  // 2048 blocks x 64 rows
  int t = threadIdx.x;
  int l = t & 63, wq = t >> 6;
  size_t row0 = (size_t)blk * 64;
  for (int e = t; e < 1536; e += 256) Gs[e] = G[row0 * 24 + e];
  // per-thread twiddles for w = l and w = l+64 (w+128 variants via parity)
  float cA[12], sA[12], cB[12], sB[12];
#pragma unroll
  for (int kx = 1; kx < 12; kx++) {
    float s, c;
    __sincosf(TPI * (float)((kx * l) & 255) * (1.0f / 256.0f), &s, &c);
    cA[kx] = c; sA[kx] = s;
    __sincosf(TPI * (float)((kx * (l + 64)) & 255) * (1.0f / 256.0f), &s, &c);
    cB[kx] = c; sB[kx] = s;
  }
  __syncthreads();
  for (int rs = 0; rs < 16; rs++) {
    int rl = wq * 16 + rs;
    float g[24];
    const float4* gr4 = reinterpret_cast<const float4*>(&Gs[rl * 24]);
#pragma unroll
    for (int q = 0; q < 6; q++) {
      float4 v = gr4[q];
      g[4 * q] = v.x; g[4 * q + 1] = v.y; g[4 * q + 2] = v.z; g[4 * q + 3] = v.w;
    }
    float EA = g[0], OA = 0, EB = g[0], OB = 0;  // DC: Re(G0) only (irfft ignores Im)
#pragma unroll
    for (int kx = 1; kx < 12; kx++) {
      float ta = g[2 * kx] * cA[kx] - g[2 * kx + 1] * sA[kx];
      float tb = g[2 * kx] * cB[kx] - g[2 * kx + 1] * sB[kx];
      if (kx & 1) { OA += ta; OB += tb; } else { EA += ta; EB += tb; }
    }
    size_t ob = (row0 + rl) * 256;
    out[ob + l] = EA + OA;
    out[ob + l + 128] = EA - OA;
    out[ob + l + 64] = EB + OB;
    out[ob + l + 192] = EB - OB;
  }
}

extern "C" void kernel_launch(void* const* d_in, const int* in_sizes, int n_in,
                              void* d_out, int out_size, void* d_ws, size_t ws_size,
                              hipStream_t stream) {
  const float* x = (const float*)d_in[0];
  const float* w1 = (const float*)d_in[1];
  const float* w2 = (const float*)d_in[2];
  float* out = (float*)d_out;
  float* ws = (float*)d_ws;

  float* X1 = ws;                       // 3,145,728 floats (12.6 MB)
  float* Xf = ws + 3145728;             //   294,912 floats
  float* Ff = ws + 3145728 + 294912;    //   294,912 floats
  float* G = ws;                        // reuse X1 space (dead after k2)

  k1_wdft<<<512, 256, 0, stream>>>(x, X1);
  k2_hdft<<<312, 256, 0, stream>>>(X1, Xf);
  k3_mix<<<288, 256, 0, stream>>>(Xf, w1, w2, Ff);
  k4_ihdft<<<256, 192, 0, stream>>>(Ff, G);
  k5_iwdft<<<2048, 256, 0, stream>>>(G, out);
}

// Round 2
// 104.050 us; speedup vs baseline: 1.2657x; 1.2657x over previous
//
#include <hip/hip_runtime.h>

// SpectralConv2d via pruned partial DFTs (h-DFT first).
// x: [16,32,256,256] f32 ; w1,w2: [32,32,12,12,2] f32 ; out: [16,32,256,256] f32
// Pipeline:
//  K1: Y[bi][j][cs][w]  = partial H-DFT: C_j[w]=sum_h x cos, S_j[w]=sum_h x sin (j=0..12)
//       (h,h+128) parity fold halves FMAs; lane=w -> coalesced reads, no x staging.
//  K2: X[ky][kx][bi]    = partial W-DFT of (C - iS) via per-thread phasor recurrence
//  K3: F[ky][kx][bo]    = channel mix (complex), scale (kx==0?1:2)/65536 folded in
//  K4: G[bo][h][kx]     = inverse ky-DFT (exact complex ifft over the 24 modes)
//  K5: out[bo][h][w]    = inverse W-DFT (real output, Hermitian doubling prefolded)

#define TPI 6.28318530717958647692f

__global__ __launch_bounds__(256) void k1_hdft(const float* __restrict__ x,
                                               float* __restrict__ Y) {
  __shared__ float tw[128 * 28];  // [h-pair 0..127][2j+{cos,sin}], 13 j's, pad to 28
  const int bi = blockIdx.x;      // 0..511
  const int t = threadIdx.x;
  const int q = t >> 6, l = t & 63;  // wave q owns w-quarter, lane l -> w = q*64+l

  for (int e = t; e < 128 * 13; e += 256) {
    int h = e / 13, j = e % 13;
    float s, c;
    sincosf(TPI * (float)((h * j) & 255) * (1.0f / 256.0f), &s, &c);
    tw[h * 28 + 2 * j] = c;
    tw[h * 28 + 2 * j + 1] = s;
  }
  __syncthreads();

  const float* xp = x + (size_t)bi * 65536 + q * 64 + l;
  float C[13], S[13];
#pragma unroll
  for (int j = 0; j < 13; j++) { C[j] = 0.0f; S[j] = 0.0f; }

#pragma unroll 4
  for (int h = 0; h < 128; h++) {
    float xa = xp[h * 256];
    float xb = xp[(h + 128) * 256];
    float xe = xa + xb, xo = xa - xb;  // even-j / odd-j folded inputs
    float r[28];
    const float4* twr = reinterpret_cast<const float4*>(&tw[h * 28]);
#pragma unroll
    for (int u = 0; u < 7; u++) {
      float4 v = twr[u];
      r[4 * u] = v.x; r[4 * u + 1] = v.y; r[4 * u + 2] = v.z; r[4 * u + 3] = v.w;
    }
#pragma unroll
    for (int j = 0; j < 13; j++) {
      float xj = (j & 1) ? xo : xe;
      C[j] = fmaf(xj, r[2 * j], C[j]);
      S[j] = fmaf(xj, r[2 * j + 1], S[j]);
    }
  }

  const int w = q * 64 + l;
  float* Yp = Y + (size_t)bi * 6656 + w;  // [bi][j][cs][256w]
#pragma unroll
  for (int j = 0; j < 13; j++) {
    Yp[(2 * j) * 256] = C[j];
    Yp[(2 * j + 1) * 256] = S[j];
  }
}

__global__ __launch_bounds__(192) void k2_wdft(const float* __restrict__ Y,
                                               float* __restrict__ Xf) {
  __shared__ float Ys[26 * 257];  // [cls][w], pad 257 (bank-spread)
  const int bi = blockIdx.x;
  const int t = threadIdx.x;
  const float* Yg = Y + (size_t)bi * 6656;
  for (int e = t; e < 6656; e += 192) Ys[(e >> 8) * 257 + (e & 255)] = Yg[e];
  __syncthreads();
  if (t >= 156) return;
  int j = t / 12, kx = t % 12;  // j = |ky| 0..12
  float cs, ss;
  {
    float s, c;
    sincosf(TPI * (float)kx * (1.0f / 256.0f), &s, &c);
    cs = c; ss = -s;  // step phasor e^{-i kx theta}
  }
  const float* Cr = &Ys[(2 * j) * 257];
  const float* Sr = &Ys[(2 * j + 1) * 257];
  float pr = 1.0f, pi = 0.0f;
  float A = 0, B = 0, D = 0, E = 0;
#pragma unroll 4
  for (int w = 0; w < 256; w++) {
    float Cv = Cr[w], Sv = Sr[w];
    A = fmaf(Cv, pr, A);
    B = fmaf(Cv, pi, B);
    D = fmaf(Sv, pr, D);
    E = fmaf(Sv, pi, E);
    float npr = pr * cs - pi * ss;
    float npi = pr * ss + pi * cs;
    pr = npr; pi = npi;
  }
  // X[ky=j]     = (C - iS)*t : re = A + E, im = B - D
  // X[ky=256-j] = (C + iS)*t : re = A - E, im = B + D  -> slot 24-j
  float2* Xo = reinterpret_cast<float2*>(Xf);
  size_t base = (size_t)kx * 512 + bi;
  if (j <= 11) Xo[(size_t)j * 12 * 512 + base] = make_float2(A + E, B - D);
  if (j >= 1)  Xo[(size_t)(24 - j) * 12 * 512 + base] = make_float2(A - E, B + D);
}

__global__ __launch_bounds__(256) void k3_mix(const float* __restrict__ Xf,
                                              const float* __restrict__ w1,
                                              const float* __restrict__ w2,
                                              float* __restrict__ Ff) {
  __shared__ float Xs[1024];  // [b][i][2]
  __shared__ float Ws[2048];  // [i][o][2]
  int m = blockIdx.x;         // ky*12 + kx, 288 blocks
  int ky = m / 12, kx = m % 12;
  int t = threadIdx.x;
  const float* Xsl = Xf + (size_t)m * 1024;
  for (int e = t; e < 1024; e += 256) Xs[e] = Xsl[e];
  const float* Wp = (ky < 12) ? w1 : w2;
  int myr = (ky < 12) ? ky : ky - 12;
  int woff = myr * 24 + kx * 2;
  for (int e = t; e < 1024; e += 256) {  // e = i*32 + o
    float2 wv = *reinterpret_cast<const float2*>(Wp + (size_t)e * 288 + woff);
    Ws[e * 2] = wv.x; Ws[e * 2 + 1] = wv.y;
  }
  __syncthreads();
  int o = t & 31, bh = t >> 5;  // bh 0..7 ; handles b = bh and bh+8
  float ar = 0, ai = 0, br = 0, bi_ = 0;
#pragma unroll
  for (int i = 0; i < 32; i++) {
    float wr = Ws[i * 64 + o * 2], wi = Ws[i * 64 + o * 2 + 1];
    float x1r = Xs[bh * 64 + i * 2], x1i = Xs[bh * 64 + i * 2 + 1];
    float x2r = Xs[(bh + 8) * 64 + i * 2], x2i = Xs[(bh + 8) * 64 + i * 2 + 1];
    ar = fmaf(x1r, wr, ar); ar = fmaf(-x1i, wi, ar);
    ai = fmaf(x1r, wi, ai); ai = fmaf(x1i, wr, ai);
    br = fmaf(x2r, wr, br); br = fmaf(-x2i, wi, br);
    bi_ = fmaf(x2r, wi, bi_); bi_ = fmaf(x2i, wr, bi_);
  }
  float scale = (kx == 0 ? 1.0f : 2.0f) * (1.0f / 65536.0f);
  float2* Fo = reinterpret_cast<float2*>(Ff) + (size_t)m * 512;
  Fo[(size_t)bh * 32 + o] = make_float2(ar * scale, ai * scale);
  Fo[(size_t)(bh + 8) * 32 + o] = make_float2(br * scale, bi_ * scale);
}

__global__ __launch_bounds__(192) void k4_ihdft(const float* __restrict__ Ff,
                                                float* __restrict__ G) {
  __shared__ float tw[8 * 13 * 2];  // [hh][j][{cos,sin}]
  int bg = blockIdx.x >> 4, hg = blockIdx.x & 15;  // 32 bo-groups x 16 h-groups
  int t = threadIdx.x;                             // 0..191
  for (int e = t; e < 8 * 13; e += 192) {
    int hh = e / 13, j = e % 13;
    float s, c;
    sincosf(TPI * (float)(((hg * 8 + hh) * j) & 255) * (1.0f / 256.0f), &s, &c);
    tw[e * 2] = c; tw[e * 2 + 1] = s;
  }
  int kx = t % 12, bl = t / 12;
  int bo = bg * 16 + bl;
  // P = F_low + F_high ; Q = i(F_low - F_high)
  float Pr[13], Pi[13], Qr[13], Qi[13];
  const float2* F2 = reinterpret_cast<const float2*>(Ff);
#pragma unroll
  for (int j = 0; j < 13; j++) {
    float lr = 0, li = 0, hr = 0, hi = 0;
    if (j < 12) { float2 v = F2[((size_t)j * 12 + kx) * 512 + bo]; lr = v.x; li = v.y; }
    if (j > 0)  { float2 v = F2[((size_t)(24 - j) * 12 + kx) * 512 + bo]; hr = v.x; hi = v.y; }
    Pr[j] = lr + hr; Pi[j] = li + hi;
    Qr[j] = hi - li; Qi[j] = lr - hr;
  }
  __syncthreads();
  float2* Go = reinterpret_cast<float2*>(G);
  for (int hh = 0; hh < 8; hh++) {
    int h = hg * 8 + hh;
    float Er = 0, Ei = 0, Or = 0, Oi = 0;  // even-j / odd-j partial sums
#pragma unroll
    for (int j = 0; j < 13; j++) {
      float c = tw[(hh * 13 + j) * 2], s = tw[(hh * 13 + j) * 2 + 1];
      if (j & 1) {
        Or = fmaf(Pr[j], c, Or); Or = fmaf(Qr[j], s, Or);
        Oi = fmaf(Pi[j], c, Oi); Oi = fmaf(Qi[j], s, Oi);
      } else {
        Er = fmaf(Pr[j], c, Er); Er = fmaf(Qr[j], s, Er);
        Ei = fmaf(Pi[j], c, Ei); Ei = fmaf(Qi[j], s, Ei);
      }
    }
    // G[h] = E + O ; G[h+128] = E - O   (e^{+-i j pi} = (-1)^j)
    size_t r0 = ((size_t)bo * 256 + h) * 12 + kx;
    size_t r1 = ((size_t)bo * 256 + h + 128) * 12 + kx;
    Go[r0] = make_float2(Er + Or, Ei + Oi);
    Go[r1] = make_float2(Er - Or, Ei - Oi);
  }
}

__global__ __launch_bounds__(256) void k5_iwdft(const float* __restrict__ G,
                                                float* __restrict__ out) {
  __shared__ float Gs[64 * 24];
  int blk = blockIdx.x;  // 2048 blocks x 64 rows
  int t = threadIdx.x;
  int l = t & 63, wq = t >> 6;
  size_t row0 = (size_t)blk * 64;
  for (int e = t; e < 1536; e += 256) Gs[e] = G[row0 * 24 + e];
  // per-thread twiddles for w = l and w = l+64 (w+128 variants via parity)
  float cA[12], sA[12], cB[12], sB[12];
#pragma unroll
  for (int kx = 1; kx < 12; kx++) {
    float s, c;
    __sincosf(TPI * (float)((kx * l) & 255) * (1.0f / 256.0f), &s, &c);
    cA[kx] = c; sA[kx] = s;
    __sincosf(TPI * (float)((kx * (l + 64)) & 255) * (1.0f / 256.0f), &s, &c);
    cB[kx] = c; sB[kx] = s;
  }
  __syncthreads();
  for (int rs = 0; rs < 16; rs++) {
    int rl = wq * 16 + rs;
    float g[24];
    const float4* gr4 = reinterpret_cast<const float4*>(&Gs[rl * 24]);
#pragma unroll
    for (int q = 0; q < 6; q++) {
      float4 v = gr4[q];
      g[4 * q] = v.x; g[4 * q + 1] = v.y; g[4 * q + 2] = v.z; g[4 * q + 3] = v.w;
    }
    float EA = g[0], OA = 0, EB = g[0], OB = 0;  // DC: Re(G0) only (irfft ignores Im)
#pragma unroll
    for (int kx = 1; kx < 12; kx++) {
      float ta = g[2 * kx] * cA[kx] - g[2 * kx + 1] * sA[kx];
      float tb = g[2 * kx] * cB[kx] - g[2 * kx + 1] * sB[kx];
      if (kx & 1) { OA += ta; OB += tb; } else { EA += ta; EB += tb; }
    }
    size_t ob = (row0 + rl) * 256;
    out[ob + l] = EA + OA;
    out[ob + l + 128] = EA - OA;
    out[ob + l + 64] = EB + OB;
    out[ob + l + 192] = EB - OB;
  }
}

extern "C" void kernel_launch(void* const* d_in, const int* in_sizes, int n_in,
                              void* d_out, int out_size, void* d_ws, size_t ws_size,
                              hipStream_t stream) {
  const float* x = (const float*)d_in[0];
  const float* w1 = (const float*)d_in[1];
  const float* w2 = (const float*)d_in[2];
  float* out = (float*)d_out;
  float* ws = (float*)d_ws;

  float* Y = ws;                        // 3,407,872 floats (13.6 MB)
  float* Xf = ws + 3407872;             //   294,912 floats
  float* Ff = ws + 3407872 + 294912;    //   294,912 floats
  float* G = ws;                        // reuse Y space (dead after k2)

  k1_hdft<<<512, 256, 0, stream>>>(x, Y);
  k2_wdft<<<512, 192, 0, stream>>>(Y, Xf);
  k3_mix<<<288, 256, 0, stream>>>(Xf, w1, w2, Ff);
  k4_ihdft<<<512, 192, 0, stream>>>(Ff, G);
  k5_iwdft<<<2048, 256, 0, stream>>>(G, out);
}

// Round 3
// 96.678 us; speedup vs baseline: 1.3622x; 1.0762x over previous
//
#include <hip/hip_runtime.h>

// SpectralConv2d via pruned partial DFTs (h-DFT first).
// x: [16,32,256,256] f32 ; w1,w2: [32,32,12,12,2] f32 ; out: [16,32,256,256] f32
// Pipeline:
//  K1: Y[bi][cls][w]    = partial H-DFT: C_j[w]=sum_h x cos, S_j[w]=sum_h x sin (j=0..12)
//       (h,h+128) parity fold halves FMAs. Thread = 4 w's (float4), wave = full w-row,
//       4 waves split h-range; register accumulators + one cross-wave LDS reduce.
//  K2: X[ky][kx][bi]    = partial W-DFT of (C - iS) via per-thread phasor recurrence
//  K3: F[ky][kx][bo]    = channel mix (complex), scale (kx==0?1:2)/65536 folded in
//  K4: G[bo][h][kx]     = inverse ky-DFT (exact complex ifft over the 24 modes)
//  K5: out[bo][h][w]    = inverse W-DFT (real output, Hermitian doubling prefolded)

#define TPI 6.28318530717958647692f

__global__ __launch_bounds__(256, 2) void k1_hdft(const float* __restrict__ x,
                                                  float* __restrict__ Y) {
  __shared__ float tw[128 * 28];        // [h-pair][2j+{cos,sin}], 13 j's, pad 28
  __shared__ float red[4 * 7 * 256];    // cross-wave reduce: [wave][class-chunk][w]
  const int bi = blockIdx.x;            // 0..511
  const int t = threadIdx.x;
  const int q = t >> 6, l = t & 63;     // wave q -> h-chunk, lane l -> w = 4l..4l+3

  for (int e = t; e < 128 * 13; e += 256) {
    int h = e / 13, j = e % 13;
    float s, c;
    sincosf(TPI * (float)((h * j) & 255) * (1.0f / 256.0f), &s, &c);
    tw[h * 28 + 2 * j] = c;
    tw[h * 28 + 2 * j + 1] = s;
  }
  __syncthreads();

  const float4* xp4 = reinterpret_cast<const float4*>(x + (size_t)bi * 65536) + l;
  float4 aC[13], aS[13];
#pragma unroll
  for (int j = 0; j < 13; j++) {
    aC[j] = make_float4(0.f, 0.f, 0.f, 0.f);
    aS[j] = make_float4(0.f, 0.f, 0.f, 0.f);
  }

  const int h0 = q * 32;
#pragma unroll 2
  for (int hh = 0; hh < 32; hh++) {
    int h = h0 + hh;
    float4 xa = xp4[h * 64];
    float4 xb = xp4[(h + 128) * 64];
    float4 xe = make_float4(xa.x + xb.x, xa.y + xb.y, xa.z + xb.z, xa.w + xb.w);
    float4 xo = make_float4(xa.x - xb.x, xa.y - xb.y, xa.z - xb.z, xa.w - xb.w);
    float r[28];
    const float4* twr = reinterpret_cast<const float4*>(&tw[h * 28]);
#pragma unroll
    for (int u = 0; u < 7; u++) {
      float4 v = twr[u];
      r[4 * u] = v.x; r[4 * u + 1] = v.y; r[4 * u + 2] = v.z; r[4 * u + 3] = v.w;
    }
#pragma unroll
    for (int j = 0; j < 13; j++) {
      float4 xj = (j & 1) ? xo : xe;
      float c = r[2 * j], s = r[2 * j + 1];
      aC[j].x = fmaf(xj.x, c, aC[j].x); aC[j].y = fmaf(xj.y, c, aC[j].y);
      aC[j].z = fmaf(xj.z, c, aC[j].z); aC[j].w = fmaf(xj.w, c, aC[j].w);
      aS[j].x = fmaf(xj.x, s, aS[j].x); aS[j].y = fmaf(xj.y, s, aS[j].y);
      aS[j].z = fmaf(xj.z, s, aS[j].z); aS[j].w = fmaf(xj.w, s, aS[j].w);
    }
  }

  // cross-wave reduce: 4 passes x 7 classes (cls = 2j for C_j, 2j+1 for S_j)
  float* Yb = Y + (size_t)bi * 6656;
  for (int p = 0; p < 4; p++) {
    __syncthreads();  // red free from previous pass
#pragma unroll
    for (int cc = 0; cc < 7; cc++) {
      int cls = p * 7 + cc;
      if (cls < 26) {
        int j = cls >> 1;
        float4 v = (cls & 1) ? aS[j] : aC[j];
        *reinterpret_cast<float4*>(&red[(q * 7 + cc) * 256 + 4 * l]) = v;
      }
    }
    __syncthreads();
    for (int idx = t; idx < 7 * 256; idx += 256) {
      int cc = idx >> 8, w = idx & 255;
      int cls = p * 7 + cc;
      if (cls < 26) {
        float s = red[(0 * 7 + cc) * 256 + w] + red[(1 * 7 + cc) * 256 + w] +
                  red[(2 * 7 + cc) * 256 + w] + red[(3 * 7 + cc) * 256 + w];
        Yb[cls * 256 + w] = s;
      }
    }
  }
}

__global__ __launch_bounds__(192) void k2_wdft(const float* __restrict__ Y,
                                               float* __restrict__ Xf) {
  __shared__ float Ys[26 * 257];  // [cls][w], pad 257 (bank-spread)
  const int bi = blockIdx.x;
  const int t = threadIdx.x;
  const float* Yg = Y + (size_t)bi * 6656;
  for (int e = t; e < 6656; e += 192) Ys[(e >> 8) * 257 + (e & 255)] = Yg[e];
  __syncthreads();
  if (t >= 156) return;
  int j = t / 12, kx = t % 12;  // j = |ky| 0..12
  float cs, ss;
  {
    float s, c;
    sincosf(TPI * (float)kx * (1.0f / 256.0f), &s, &c);
    cs = c; ss = -s;  // step phasor e^{-i kx theta}
  }
  const float* Cr = &Ys[(2 * j) * 257];
  const float* Sr = &Ys[(2 * j + 1) * 257];
  float pr = 1.0f, pi = 0.0f;
  float A = 0, B = 0, D = 0, E = 0;
#pragma unroll 4
  for (int w = 0; w < 256; w++) {
    float Cv = Cr[w], Sv = Sr[w];
    A = fmaf(Cv, pr, A);
    B = fmaf(Cv, pi, B);
    D = fmaf(Sv, pr, D);
    E = fmaf(Sv, pi, E);
    float npr = pr * cs - pi * ss;
    float npi = pr * ss + pi * cs;
    pr = npr; pi = npi;
  }
  // X[ky=j]     = (C - iS)*t : re = A + E, im = B - D
  // X[ky=256-j] = (C + iS)*t : re = A - E, im = B + D  -> slot 24-j
  float2* Xo = reinterpret_cast<float2*>(Xf);
  size_t base = (size_t)kx * 512 + bi;
  if (j <= 11) Xo[(size_t)j * 12 * 512 + base] = make_float2(A + E, B - D);
  if (j >= 1)  Xo[(size_t)(24 - j) * 12 * 512 + base] = make_float2(A - E, B + D);
}

__global__ __launch_bounds__(256) void k3_mix(const float* __restrict__ Xf,
                                              const float* __restrict__ w1,
                                              const float* __restrict__ w2,
                                              float* __restrict__ Ff) {
  __shared__ float Xs[1024];  // [b][i][2]
  __shared__ float Ws[2048];  // [i][o][2]
  int m = blockIdx.x;         // ky*12 + kx, 288 blocks
  int ky = m / 12, kx = m % 12;
  int t = threadIdx.x;
  const float* Xsl = Xf + (size_t)m * 1024;
  for (int e = t; e < 1024; e += 256) Xs[e] = Xsl[e];
  const float* Wp = (ky < 12) ? w1 : w2;
  int myr = (ky < 12) ? ky : ky - 12;
  int woff = myr * 24 + kx * 2;
  for (int e = t; e < 1024; e += 256) {  // e = i*32 + o
    float2 wv = *reinterpret_cast<const float2*>(Wp + (size_t)e * 288 + woff);
    Ws[e * 2] = wv.x; Ws[e * 2 + 1] = wv.y;
  }
  __syncthreads();
  int o = t & 31, bh = t >> 5;  // bh 0..7 ; handles b = bh and bh+8
  float ar = 0, ai = 0, br = 0, bi_ = 0;
#pragma unroll
  for (int i = 0; i < 32; i++) {
    float wr = Ws[i * 64 + o * 2], wi = Ws[i * 64 + o * 2 + 1];
    float x1r = Xs[bh * 64 + i * 2], x1i = Xs[bh * 64 + i * 2 + 1];
    float x2r = Xs[(bh + 8) * 64 + i * 2], x2i = Xs[(bh + 8) * 64 + i * 2 + 1];
    ar = fmaf(x1r, wr, ar); ar = fmaf(-x1i, wi, ar);
    ai = fmaf(x1r, wi, ai); ai = fmaf(x1i, wr, ai);
    br = fmaf(x2r, wr, br); br = fmaf(-x2i, wi, br);
    bi_ = fmaf(x2r, wi, bi_); bi_ = fmaf(x2i, wr, bi_);
  }
  float scale = (kx == 0 ? 1.0f : 2.0f) * (1.0f / 65536.0f);
  float2* Fo = reinterpret_cast<float2*>(Ff) + (size_t)m * 512;
  Fo[(size_t)bh * 32 + o] = make_float2(ar * scale, ai * scale);
  Fo[(size_t)(bh + 8) * 32 + o] = make_float2(br * scale, bi_ * scale);
}

__global__ __launch_bounds__(192) void k4_ihdft(const float* __restrict__ Ff,
                                                float* __restrict__ G) {
  __shared__ float tw[8 * 13 * 2];  // [hh][j][{cos,sin}]
  int bg = blockIdx.x >> 4, hg = blockIdx.x & 15;  // 32 bo-groups x 16 h-groups
  int t = threadIdx.x;                             // 0..191
  for (int e = t; e < 8 * 13; e += 192) {
    int hh = e / 13, j = e % 13;
    float s, c;
    sincosf(TPI * (float)(((hg * 8 + hh) * j) & 255) * (1.0f / 256.0f), &s, &c);
    tw[e * 2] = c; tw[e * 2 + 1] = s;
  }
  int kx = t % 12, bl = t / 12;
  int bo = bg * 16 + bl;
  // P = F_low + F_high ; Q = i(F_low - F_high)
  float Pr[13], Pi[13], Qr[13], Qi[13];
  const float2* F2 = reinterpret_cast<const float2*>(Ff);
#pragma unroll
  for (int j = 0; j < 13; j++) {
    float lr = 0, li = 0, hr = 0, hi = 0;
    if (j < 12) { float2 v = F2[((size_t)j * 12 + kx) * 512 + bo]; lr = v.x; li = v.y; }
    if (j > 0)  { float2 v = F2[((size_t)(24 - j) * 12 + kx) * 512 + bo]; hr = v.x; hi = v.y; }
    Pr[j] = lr + hr; Pi[j] = li + hi;
    Qr[j] = hi - li; Qi[j] = lr - hr;
  }
  __syncthreads();
  float2* Go = reinterpret_cast<float2*>(G);
  for (int hh = 0; hh < 8; hh++) {
    int h = hg * 8 + hh;
    float Er = 0, Ei = 0, Or = 0, Oi = 0;  // even-j / odd-j partial sums
#pragma unroll
    for (int j = 0; j < 13; j++) {
      float c = tw[(hh * 13 + j) * 2], s = tw[(hh * 13 + j) * 2 + 1];
      if (j & 1) {
        Or = fmaf(Pr[j], c, Or); Or = fmaf(Qr[j], s, Or);
        Oi = fmaf(Pi[j], c, Oi); Oi = fmaf(Qi[j], s, Oi);
      } else {
        Er = fmaf(Pr[j], c, Er); Er = fmaf(Qr[j], s, Er);
        Ei = fmaf(Pi[j], c, Ei); Ei = fmaf(Qi[j], s, Ei);
      }
    }
    // G[h] = E + O ; G[h+128] = E - O   (e^{+-i j pi} = (-1)^j)
    size_t r0 = ((size_t)bo * 256 + h) * 12 + kx;
    size_t r1 = ((size_t)bo * 256 + h + 128) * 12 + kx;
    Go[r0] = make_float2(Er + Or, Ei + Oi);
    Go[r1] = make_float2(Er - Or, Ei - Oi);
  }
}

__global__ __launch_bounds__(256) void k5_iwdft(const float* __restrict__ G,
                                                float* __restrict__ out) {
  __shared__ float Gs[64 * 24];
  int blk = blockIdx.x;  // 2048 blocks x 64 rows
  int t = threadIdx.x;
  int l = t & 63, wq = t >> 6;
  size_t row0 = (size_t)blk * 64;
  for (int e = t; e < 1536; e += 256) Gs[e] = G[row0 * 24 + e];
  // per-thread twiddles for w = l and w = l+64 (w+128 variants via parity)
  float cA[12], sA[12], cB[12], sB[12];
#pragma unroll
  for (int kx = 1; kx < 12; kx++) {
    float s, c;
    __sincosf(TPI * (float)((kx * l) & 255) * (1.0f / 256.0f), &s, &c);
    cA[kx] = c; sA[kx] = s;
    __sincosf(TPI * (float)((kx * (l + 64)) & 255) * (1.0f / 256.0f), &s, &c);
    cB[kx] = c; sB[kx] = s;
  }
  __syncthreads();
  for (int rs = 0; rs < 16; rs++) {
    int rl = wq * 16 + rs;
    float g[24];
    const float4* gr4 = reinterpret_cast<const float4*>(&Gs[rl * 24]);
#pragma unroll
    for (int q = 0; q < 6; q++) {
      float4 v = gr4[q];
      g[4 * q] = v.x; g[4 * q + 1] = v.y; g[4 * q + 2] = v.z; g[4 * q + 3] = v.w;
    }
    float EA = g[0], OA = 0, EB = g[0], OB = 0;  // DC: Re(G0) only (irfft ignores Im)
#pragma unroll
    for (int kx = 1; kx < 12; kx++) {
      float ta = g[2 * kx] * cA[kx] - g[2 * kx + 1] * sA[kx];
      float tb = g[2 * kx] * cB[kx] - g[2 * kx + 1] * sB[kx];
      if (kx & 1) { OA += ta; OB += tb; } else { EA += ta; EB += tb; }
    }
    size_t ob = (row0 + rl) * 256;
    out[ob + l] = EA + OA;
    out[ob + l + 128] = EA - OA;
    out[ob + l + 64] = EB + OB;
    out[ob + l + 192] = EB - OB;
  }
}

extern "C" void kernel_launch(void* const* d_in, const int* in_sizes, int n_in,
                              void* d_out, int out_size, void* d_ws, size_t ws_size,
                              hipStream_t stream) {
  const float* x = (const float*)d_in[0];
  const float* w1 = (const float*)d_in[1];
  const float* w2 = (const float*)d_in[2];
  float* out = (float*)d_out;
  float* ws = (float*)d_ws;

  float* Y = ws;                        // 3,407,872 floats (13.6 MB)
  float* Xf = ws + 3407872;             //   294,912 floats
  float* Ff = ws + 3407872 + 294912;    //   294,912 floats
  float* G = ws;                        // reuse Y space (dead after k2)

  k1_hdft<<<512, 256, 0, stream>>>(x, Y);
  k2_wdft<<<512, 192, 0, stream>>>(Y, Xf);
  k3_mix<<<288, 256, 0, stream>>>(Xf, w1, w2, Ff);
  k4_ihdft<<<512, 192, 0, stream>>>(Ff, G);
  k5_iwdft<<<2048, 256, 0, stream>>>(G, out);
}

// Round 4
// 91.760 us; speedup vs baseline: 1.4352x; 1.0536x over previous
//
#include <hip/hip_runtime.h>

// SpectralConv2d via pruned partial DFTs (h-DFT first).
// x: [16,32,256,256] f32 ; w1,w2: [32,32,12,12,2] f32 ; out: [16,32,256,256] f32
// Pipeline:
//  K1: Y[bi][cls][w]    = partial H-DFT: C_j[w]=sum_h x cos, S_j[w]=sum_h x sin (j=0..12)
//       (h,h+128) parity fold halves FMAs. Block = (bi, w-half): grid 1024 -> 4 blocks/CU,
//       16 waves/CU. Thread = 2 w's (float2), 4 waves split h; register acc + LDS reduce.
//  K2: X[ky][kx][bi]    = partial W-DFT of (C - iS) via per-thread phasor recurrence
//  K3: F[ky][kx][bo]    = channel mix (complex), scale (kx==0?1:2)/65536 folded in
//  K4: G[bo][h][kx]     = inverse ky-DFT (exact complex ifft over the 24 modes)
//  K5: out[bo][h][w]    = inverse W-DFT (real output, Hermitian doubling prefolded)

#define TPI 6.28318530717958647692f

__global__ __launch_bounds__(256, 4) void k1_hdft(const float* __restrict__ x,
                                                  float* __restrict__ Y) {
  __shared__ float tw[128 * 28];      // [h-pair][2j+{cos,sin}], 13 j's, pad 28 (14 KB)
  __shared__ float red[4 * 7 * 128];  // cross-wave reduce (14 KB)
  const int blk = blockIdx.x;         // 0..1023 = bi*2 + wh
  const int bi = blk >> 1, wh = blk & 1;
  const int t = threadIdx.x;
  const int q = t >> 6, l = t & 63;   // wave q -> h-chunk, lane l -> w = wh*128 + 2l{,+1}

  for (int e = t; e < 128 * 13; e += 256) {
    int h = e / 13, j = e % 13;
    float s, c;
    sincosf(TPI * (float)((h * j) & 255) * (1.0f / 256.0f), &s, &c);
    tw[h * 28 + 2 * j] = c;
    tw[h * 28 + 2 * j + 1] = s;
  }
  __syncthreads();

  const float2* xp2 = reinterpret_cast<const float2*>(x + (size_t)bi * 65536 + wh * 128) + l;
  float2 aC[13], aS[13];
#pragma unroll
  for (int j = 0; j < 13; j++) {
    aC[j] = make_float2(0.f, 0.f);
    aS[j] = make_float2(0.f, 0.f);
  }

  const int h0 = q * 32;
#pragma unroll 2
  for (int hh = 0; hh < 32; hh++) {
    int h = h0 + hh;
    float2 xa = xp2[h * 128];          // row stride = 128 float2
    float2 xb = xp2[(h + 128) * 128];
    float2 xe = make_float2(xa.x + xb.x, xa.y + xb.y);
    float2 xo = make_float2(xa.x - xb.x, xa.y - xb.y);
    const float4* twr = reinterpret_cast<const float4*>(&tw[h * 28]);
#pragma unroll
    for (int u = 0; u < 6; u++) {      // classes 4u..4u+3 : j0=2u (even->xe), j1=2u+1 (odd->xo)
      float4 v = twr[u];
      int j0 = 2 * u, j1 = 2 * u + 1;
      aC[j0].x = fmaf(xe.x, v.x, aC[j0].x); aC[j0].y = fmaf(xe.y, v.x, aC[j0].y);
      aS[j0].x = fmaf(xe.x, v.y, aS[j0].x); aS[j0].y = fmaf(xe.y, v.y, aS[j0].y);
      aC[j1].x = fmaf(xo.x, v.z, aC[j1].x); aC[j1].y = fmaf(xo.y, v.z, aC[j1].y);
      aS[j1].x = fmaf(xo.x, v.w, aS[j1].x); aS[j1].y = fmaf(xo.y, v.w, aS[j1].y);
    }
    {
      float4 v = twr[6];               // classes 24,25 = j=12 (even->xe); 26,27 pad
      aC[12].x = fmaf(xe.x, v.x, aC[12].x); aC[12].y = fmaf(xe.y, v.x, aC[12].y);
      aS[12].x = fmaf(xe.x, v.y, aS[12].x); aS[12].y = fmaf(xe.y, v.y, aS[12].y);
    }
  }

  // cross-wave reduce: 4 passes x 7 classes (cls = 2j for C_j, 2j+1 for S_j)
  float* Yb = Y + (size_t)bi * 6656 + wh * 128;
  for (int p = 0; p < 4; p++) {
    __syncthreads();  // red free from previous pass
#pragma unroll
    for (int cc = 0; cc < 7; cc++) {
      int cls = p * 7 + cc;
      if (cls < 26) {
        int j = cls >> 1;
        float2 v = (cls & 1) ? aS[j] : aC[j];
        *reinterpret_cast<float2*>(&red[(q * 7 + cc) * 128 + 2 * l]) = v;
      }
    }
    __syncthreads();
    for (int idx = t; idx < 7 * 128; idx += 256) {
      int cc = idx >> 7, wl = idx & 127;
      int cls = p * 7 + cc;
      if (cls < 26) {
        float s = red[(0 * 7 + cc) * 128 + wl] + red[(1 * 7 + cc) * 128 + wl] +
                  red[(2 * 7 + cc) * 128 + wl] + red[(3 * 7 + cc) * 128 + wl];
        Yb[cls * 256 + wl] = s;
      }
    }
  }
}

__global__ __launch_bounds__(192) void k2_wdft(const float* __restrict__ Y,
                                               float* __restrict__ Xf) {
  __shared__ float Ys[26 * 257];  // [cls][w], pad 257 (bank-spread)
  const int bi = blockIdx.x;
  const int t = threadIdx.x;
  const float* Yg = Y + (size_t)bi * 6656;
  for (int e = t; e < 6656; e += 192) Ys[(e >> 8) * 257 + (e & 255)] = Yg[e];
  __syncthreads();
  if (t >= 156) return;
  int j = t / 12, kx = t % 12;  // j = |ky| 0..12
  float cs, ss;
  {
    float s, c;
    sincosf(TPI * (float)kx * (1.0f / 256.0f), &s, &c);
    cs = c; ss = -s;  // step phasor e^{-i kx theta}
  }
  const float* Cr = &Ys[(2 * j) * 257];
  const float* Sr = &Ys[(2 * j + 1) * 257];
  float pr = 1.0f, pi = 0.0f;
  float A = 0, B = 0, D = 0, E = 0;
#pragma unroll 4
  for (int w = 0; w < 256; w++) {
    float Cv = Cr[w], Sv = Sr[w];
    A = fmaf(Cv, pr, A);
    B = fmaf(Cv, pi, B);
    D = fmaf(Sv, pr, D);
    E = fmaf(Sv, pi, E);
    float npr = pr * cs - pi * ss;
    float npi = pr * ss + pi * cs;
    pr = npr; pi = npi;
  }
  // X[ky=j]     = (C - iS)*t : re = A + E, im = B - D
  // X[ky=256-j] = (C + iS)*t : re = A - E, im = B + D  -> slot 24-j
  float2* Xo = reinterpret_cast<float2*>(Xf);
  size_t base = (size_t)kx * 512 + bi;
  if (j <= 11) Xo[(size_t)j * 12 * 512 + base] = make_float2(A + E, B - D);
  if (j >= 1)  Xo[(size_t)(24 - j) * 12 * 512 + base] = make_float2(A - E, B + D);
}

__global__ __launch_bounds__(256) void k3_mix(const float* __restrict__ Xf,
                                              const float* __restrict__ w1,
                                              const float* __restrict__ w2,
                                              float* __restrict__ Ff) {
  __shared__ float Xs[1024];  // [b][i][2]
  __shared__ float Ws[2048];  // [i][o][2]
  int m = blockIdx.x;         // ky*12 + kx, 288 blocks
  int ky = m / 12, kx = m % 12;
  int t = threadIdx.x;
  const float* Xsl = Xf + (size_t)m * 1024;
  for (int e = t; e < 1024; e += 256) Xs[e] = Xsl[e];
  const float* Wp = (ky < 12) ? w1 : w2;
  int myr = (ky < 12) ? ky : ky - 12;
  int woff = myr * 24 + kx * 2;
  for (int e = t; e < 1024; e += 256) {  // e = i*32 + o
    float2 wv = *reinterpret_cast<const float2*>(Wp + (size_t)e * 288 + woff);
    Ws[e * 2] = wv.x; Ws[e * 2 + 1] = wv.y;
  }
  __syncthreads();
  int o = t & 31, bh = t >> 5;  // bh 0..7 ; handles b = bh and bh+8
  float ar = 0, ai = 0, br = 0, bi_ = 0;
#pragma unroll
  for (int i = 0; i < 32; i++) {
    float wr = Ws[i * 64 + o * 2], wi = Ws[i * 64 + o * 2 + 1];
    float x1r = Xs[bh * 64 + i * 2], x1i = Xs[bh * 64 + i * 2 + 1];
    float x2r = Xs[(bh + 8) * 64 + i * 2], x2i = Xs[(bh + 8) * 64 + i * 2 + 1];
    ar = fmaf(x1r, wr, ar); ar = fmaf(-x1i, wi, ar);
    ai = fmaf(x1r, wi, ai); ai = fmaf(x1i, wr, ai);
    br = fmaf(x2r, wr, br); br = fmaf(-x2i, wi, br);
    bi_ = fmaf(x2r, wi, bi_); bi_ = fmaf(x2i, wr, bi_);
  }
  float scale = (kx == 0 ? 1.0f : 2.0f) * (1.0f / 65536.0f);
  float2* Fo = reinterpret_cast<float2*>(Ff) + (size_t)m * 512;
  Fo[(size_t)bh * 32 + o] = make_float2(ar * scale, ai * scale);
  Fo[(size_t)(bh + 8) * 32 + o] = make_float2(br * scale, bi_ * scale);
}

__global__ __launch_bounds__(192) void k4_ihdft(const float* __restrict__ Ff,
                                                float* __restrict__ G) {
  __shared__ float tw[8 * 13 * 2];  // [hh][j][{cos,sin}]
  int bg = blockIdx.x >> 4, hg = blockIdx.x & 15;  // 32 bo-groups x 16 h-groups
  int t = threadIdx.x;                             // 0..191
  for (int e = t; e < 8 * 13; e += 192) {
    int hh = e / 13, j = e % 13;
    float s, c;
    sincosf(TPI * (float)(((hg * 8 + hh) * j) & 255) * (1.0f / 256.0f), &s, &c);
    tw[e * 2] = c; tw[e * 2 + 1] = s;
  }
  int kx = t % 12, bl = t / 12;
  int bo = bg * 16 + bl;
  // P = F_low + F_high ; Q = i(F_low - F_high)
  float Pr[13], Pi[13], Qr[13], Qi[13];
  const float2* F2 = reinterpret_cast<const float2*>(Ff);
#pragma unroll
  for (int j = 0; j < 13; j++) {
    float lr = 0, li = 0, hr = 0, hi = 0;
    if (j < 12) { float2 v = F2[((size_t)j * 12 + kx) * 512 + bo]; lr = v.x; li = v.y; }
    if (j > 0)  { float2 v = F2[((size_t)(24 - j) * 12 + kx) * 512 + bo]; hr = v.x; hi = v.y; }
    Pr[j] = lr + hr; Pi[j] = li + hi;
    Qr[j] = hi - li; Qi[j] = lr - hr;
  }
  __syncthreads();
  float2* Go = reinterpret_cast<float2*>(G);
  for (int hh = 0; hh < 8; hh++) {
    int h = hg * 8 + hh;
    float Er = 0, Ei = 0, Or = 0, Oi = 0;  // even-j / odd-j partial sums
#pragma unroll
    for (int j = 0; j < 13; j++) {
      float c = tw[(hh * 13 + j) * 2], s = tw[(hh * 13 + j) * 2 + 1];
      if (j & 1) {
        Or = fmaf(Pr[j], c, Or); Or = fmaf(Qr[j], s, Or);
        Oi = fmaf(Pi[j], c, Oi); Oi = fmaf(Qi[j], s, Oi);
      } else {
        Er = fmaf(Pr[j], c, Er); Er = fmaf(Qr[j], s, Er);
        Ei = fmaf(Pi[j], c, Ei); Ei = fmaf(Qi[j], s, Ei);
      }
    }
    // G[h] = E + O ; G[h+128] = E - O   (e^{+-i j pi} = (-1)^j)
    size_t r0 = ((size_t)bo * 256 + h) * 12 + kx;
    size_t r1 = ((size_t)bo * 256 + h + 128) * 12 + kx;
    Go[r0] = make_float2(Er + Or, Ei + Oi);
    Go[r1] = make_float2(Er - Or, Ei - Oi);
  }
}

__global__ __launch_bounds__(256) void k5_iwdft(const float* __restrict__ G,
                                                float* __restrict__ out) {
  __shared__ float Gs[64 * 24];
  int blk = blockIdx.x;  // 2048 blocks x 64 rows
  int t = threadIdx.x;
  int l = t & 63, wq = t >> 6;
  size_t row0 = (size_t)blk * 64;
  for (int e = t; e < 1536; e += 256) Gs[e] = G[row0 * 24 + e];
  // lane handles w0 = 2l, w1 = 2l+1 (and +128 partners via parity) -> float2 stores
  float cA[12], sA[12], cB[12], sB[12];
#pragma unroll
  for (int kx = 1; kx < 12; kx++) {
    float s, c;
    __sincosf(TPI * (float)((kx * (2 * l)) & 255) * (1.0f / 256.0f), &s, &c);
    cA[kx] = c; sA[kx] = s;
    __sincosf(TPI * (float)((kx * (2 * l + 1)) & 255) * (1.0f / 256.0f), &s, &c);
    cB[kx] = c; sB[kx] = s;
  }
  __syncthreads();
  for (int rs = 0; rs < 16; rs++) {
    int rl = wq * 16 + rs;
    float g[24];
    const float4* gr4 = reinterpret_cast<const float4*>(&Gs[rl * 24]);
#pragma unroll
    for (int q = 0; q < 6; q++) {
      float4 v = gr4[q];
      g[4 * q] = v.x; g[4 * q + 1] = v.y; g[4 * q + 2] = v.z; g[4 * q + 3] = v.w;
    }
    float E0 = g[0], O0 = 0, E1 = g[0], O1 = 0;  // DC: Re(G0) only (irfft ignores Im)
#pragma unroll
    for (int kx = 1; kx < 12; kx++) {
      float ta = g[2 * kx] * cA[kx] - g[2 * kx + 1] * sA[kx];
      float tb = g[2 * kx] * cB[kx] - g[2 * kx + 1] * sB[kx];
      if (kx & 1) { O0 += ta; O1 += tb; } else { E0 += ta; E1 += tb; }
    }
    size_t ob = (row0 + rl) * 256;
    *reinterpret_cast<float2*>(&out[ob + 2 * l]) = make_float2(E0 + O0, E1 + O1);
    *reinterpret_cast<float2*>(&out[ob + 128 + 2 * l]) = make_float2(E0 - O0, E1 - O1);
  }
}

extern "C" void kernel_launch(void* const* d_in, const int* in_sizes, int n_in,
                              void* d_out, int out_size, void* d_ws, size_t ws_size,
                              hipStream_t stream) {
  const float* x = (const float*)d_in[0];
  const float* w1 = (const float*)d_in[1];
  const float* w2 = (const float*)d_in[2];
  float* out = (float*)d_out;
  float* ws = (float*)d_ws;

  float* Y = ws;                        // 3,407,872 floats (13.6 MB)
  float* Xf = ws + 3407872;             //   294,912 floats
  float* Ff = ws + 3407872 + 294912;    //   294,912 floats
  float* G = ws;                        // reuse Y space (dead after k2)

  k1_hdft<<<1024, 256, 0, stream>>>(x, Y);
  k2_wdft<<<512, 192, 0, stream>>>(Y, Xf);
  k3_mix<<<288, 256, 0, stream>>>(Xf, w1, w2, Ff);
  k4_ihdft<<<512, 192, 0, stream>>>(Ff, G);
  k5_iwdft<<<2048, 256, 0, stream>>>(G, out);
}